// Round 9
// baseline (3306.064 us; speedup 1.0000x reference)
//
#include <hip/hip_runtime.h>
#include <hip/hip_fp16.h>

#define N_ATOMS 200000
#define N_BONDS 400000
#define MAX_NEI 10
#define N_MOLS  8000
#define AFD 87
#define BFD 6
#define H 64
#define WPB 16          // waves per block (1024 threads)
#define RPW 4           // rows per wave
#define RPB (WPB*RPW)   // 64 rows per block
#define NG  (RPW*MAX_NEI)   // 40 neighbor slots per wave

#define NT_LD(p)     __builtin_nontemporal_load(p)
#define NT_ST(p, v)  __builtin_nontemporal_store((v), (p))

// ---------------------------------------------------------------------------
// T: M1 = W_bemb @ V1 ; M2 = W_bemb @ W1   (both [6][64], one block)
// ---------------------------------------------------------------------------
__global__ __launch_bounds__(256) void k_tiny(
    const float* __restrict__ Wb, const float* __restrict__ V1,
    const float* __restrict__ W1, float* __restrict__ M1, float* __restrict__ M2)
{
    int t = threadIdx.x;
    for (int idx = t; idx < BFD * H; idx += 256) {
        int k = idx >> 6, h = idx & 63;
        float a1 = 0.f, a2 = 0.f;
        for (int j = 0; j < H; ++j) {
            float w = Wb[k * H + j];
            a1 = fmaf(w, V1[j * H + h], a1);
            a2 = fmaf(w, W1[j * H + h], a2);
        }
        M1[idx] = a1;
        M2[idx] = a2;
    }
}

// ---------------------------------------------------------------------------
// A: h_atom = af@Wemb ; g_atom0 = h_atom@V2 (fp16 out). 4 rows/wave.
// ---------------------------------------------------------------------------
__global__ __launch_bounds__(1024, 8) void k_atom_emb(
    const float* __restrict__ af, const float* __restrict__ Wemb,
    const float* __restrict__ V2, float* __restrict__ h_atom,
    __half* __restrict__ g_atom)
{
    __shared__ float sW[AFD * H];          // 22272 B
    __shared__ float sV[H * H];            // 16384 B
    __shared__ float sT[WPB * AFD * 4];    // 22272 B
    int tid = threadIdx.x;
    for (int t = tid; t < AFD * H / 4; t += 1024)
        ((float4*)sW)[t] = ((const float4*)Wemb)[t];
    ((float4*)sV)[tid] = ((const float4*)V2)[tid];
    int w = tid >> 6, h = tid & 63;
    int row0 = __builtin_amdgcn_readfirstlane((int)(blockIdx.x * RPB + w * RPW));
    float* myT = sT + w * (AFD * 4);
    for (int c = h; c < AFD; c += 64) {
#pragma unroll
        for (int i = 0; i < RPW; ++i)
            myT[c * 4 + i] = NT_LD(&af[(size_t)(row0 + i) * AFD + c]);
    }
    __syncthreads();
    const float4* myTv = (const float4*)myT;
    float a0 = 0.f, a1 = 0.f, a2 = 0.f, a3 = 0.f;
#pragma unroll 4
    for (int k = 0; k < AFD; ++k) {
        float u = sW[k * H + h];
        float4 s = myTv[k];
        a0 = fmaf(s.x, u, a0); a1 = fmaf(s.y, u, a1);
        a2 = fmaf(s.z, u, a2); a3 = fmaf(s.w, u, a3);
    }
    NT_ST(&h_atom[(size_t)(row0 + 0) * H + h], a0);
    NT_ST(&h_atom[(size_t)(row0 + 1) * H + h], a1);
    NT_ST(&h_atom[(size_t)(row0 + 2) * H + h], a2);
    NT_ST(&h_atom[(size_t)(row0 + 3) * H + h], a3);
    ((float4*)myT)[h] = make_float4(a0, a1, a2, a3);
    float g0 = 0.f, g1 = 0.f, g2 = 0.f, g3 = 0.f;
#pragma unroll 4
    for (int k = 0; k < H; ++k) {
        float v = sV[k * H + h];
        float4 s = myTv[k];
        g0 = fmaf(s.x, v, g0); g1 = fmaf(s.y, v, g1);
        g2 = fmaf(s.z, v, g2); g3 = fmaf(s.w, v, g3);
    }
    g_atom[(size_t)(row0 + 0) * H + h] = __float2half(g0);
    g_atom[(size_t)(row0 + 1) * H + h] = __float2half(g1);
    g_atom[(size_t)(row0 + 2) * H + h] = __float2half(g2);
    g_atom[(size_t)(row0 + 3) * H + h] = __float2half(g3);
}

// ---------------------------------------------------------------------------
// E: h_new = relu(h@U1 + nei@U2); extra = h_new@Mx (fp16 out). 4 rows/wave.
// 2-stage, 10-wide software-pipelined gathers; indices via one 40-lane load
// + readlane broadcast; bond rows via one 60-lane scattered load + bpermute.
// ---------------------------------------------------------------------------
#define ISSUE_NEI(i, GA, BV) do {                                            \
    _Pragma("unroll")                                                        \
    for (int j = 0; j < MAX_NEI; ++j) {                                      \
        int idx = __shfl(my_ia, (i) * MAX_NEI + j, 64);                      \
        GA[j] = g_atom[(size_t)idx * H + h];                                 \
    }                                                                        \
    int ibk = __shfl(my_ib, (i) * MAX_NEI + kk, 64);                         \
    BV = (h < MAX_NEI * BFD) ? bf[(size_t)ibk * BFD + jj] : 0.f;             \
} while (0)

#define CONSUME_NEI(GA, BV, OUT) do {                                        \
    float a = 0.f;                                                           \
    _Pragma("unroll")                                                        \
    for (int j = 0; j < MAX_NEI; ++j) {                                      \
        float gb = 0.f;                                                      \
        _Pragma("unroll")                                                    \
        for (int q = 0; q < BFD; ++q)                                        \
            gb = fmaf(__shfl(BV, j * BFD + q, 64), m1c[q], gb);              \
        a += fmaxf(gb + __half2float(GA[j]), 0.f);                           \
    }                                                                        \
    OUT = a;                                                                 \
} while (0)

__global__ __launch_bounds__(1024, 8) void k_update(
    const float* __restrict__ h_in, const __half* __restrict__ g_atom,
    const float* __restrict__ bf, const float* __restrict__ M1,
    const int* __restrict__ ag, const int* __restrict__ bg,
    const float* __restrict__ U1, const float* __restrict__ U2,
    const float* __restrict__ Mx,
    float* __restrict__ h_out, __half* __restrict__ extra_out)
{
    __shared__ float sU1[H * H];        // 16 KB
    __shared__ float sU2[H * H];        // 16 KB
    __shared__ float4 sRow[WPB][H];     // 16 KB
    __shared__ float4 sNei[WPB][H];     // 16 KB
    int tid = threadIdx.x;
    ((float4*)sU1)[tid] = ((const float4*)U1)[tid];
    ((float4*)sU2)[tid] = ((const float4*)U2)[tid];
    int w = tid >> 6, h = tid & 63;
    int kk = h / BFD;                    // neighbor slot for bond-feat load
    int jj = h - kk * BFD;               // feature index
    int row0 = __builtin_amdgcn_readfirstlane((int)(blockIdx.x * RPB + w * RPW));

    // all 40 indices in one coalesced 40-lane load per table
    int my_ia = 0, my_ib = 0;
    if (h < NG) {
        my_ia = ag[(size_t)row0 * MAX_NEI + h];
        my_ib = bg[(size_t)row0 * MAX_NEI + h];
    }
    float m1c[BFD];
#pragma unroll
    for (int j = 0; j < BFD; ++j) m1c[j] = M1[j * H + h];
    float x0 = NT_LD(&h_in[(size_t)(row0 + 0) * H + h]);
    float x1 = NT_LD(&h_in[(size_t)(row0 + 1) * H + h]);
    float x2 = NT_LD(&h_in[(size_t)(row0 + 2) * H + h]);
    float x3 = NT_LD(&h_in[(size_t)(row0 + 3) * H + h]);
    sRow[w][h] = make_float4(x0, x1, x2, x3);

    __half ga_A[MAX_NEI], ga_B[MAX_NEI];
    float bv_A, bv_B;
    ISSUE_NEI(0, ga_A, bv_A);
    ISSUE_NEI(1, ga_B, bv_B);

    __syncthreads();                     // weights ready; gathers in flight

    // U1 matmul overlaps rows-0/1 gathers
    float o0 = 0.f, o1 = 0.f, o2 = 0.f, o3 = 0.f;
#pragma unroll 4
    for (int k = 0; k < H; ++k) {
        float u = sU1[k * H + h];
        float4 s = sRow[w][k];
        o0 = fmaf(s.x, u, o0); o1 = fmaf(s.y, u, o1);
        o2 = fmaf(s.z, u, o2); o3 = fmaf(s.w, u, o3);
    }

    float n0, n1, n2, n3;
    CONSUME_NEI(ga_A, bv_A, n0);
    ISSUE_NEI(2, ga_A, bv_A);
    CONSUME_NEI(ga_B, bv_B, n1);
    ISSUE_NEI(3, ga_B, bv_B);
    CONSUME_NEI(ga_A, bv_A, n2);
    CONSUME_NEI(ga_B, bv_B, n3);
    sNei[w][h] = make_float4(n0, n1, n2, n3);   // own-wave use only

#pragma unroll 4
    for (int k = 0; k < H; ++k) {
        float u = sU2[k * H + h];
        float4 s = sNei[w][k];
        o0 = fmaf(s.x, u, o0); o1 = fmaf(s.y, u, o1);
        o2 = fmaf(s.z, u, o2); o3 = fmaf(s.w, u, o3);
    }
    o0 = fmaxf(o0, 0.f); o1 = fmaxf(o1, 0.f);
    o2 = fmaxf(o2, 0.f); o3 = fmaxf(o3, 0.f);
    NT_ST(&h_out[(size_t)(row0 + 0) * H + h], o0);
    NT_ST(&h_out[(size_t)(row0 + 1) * H + h], o1);
    NT_ST(&h_out[(size_t)(row0 + 2) * H + h], o2);
    NT_ST(&h_out[(size_t)(row0 + 3) * H + h], o3);
    sRow[w][h] = make_float4(o0, o1, o2, o3);   // reuse as h_new (own wave)
    float g0 = 0.f, g1 = 0.f, g2 = 0.f, g3 = 0.f;
#pragma unroll 4
    for (int k = 0; k < H; ++k) {
        float u = Mx[k * H + h];                // L1/L2-resident 16 KB
        float4 s = sRow[w][k];
        g0 = fmaf(s.x, u, g0); g1 = fmaf(s.y, u, g1);
        g2 = fmaf(s.z, u, g2); g3 = fmaf(s.w, u, g3);
    }
    extra_out[(size_t)(row0 + 0) * H + h] = __float2half(g0);
    extra_out[(size_t)(row0 + 1) * H + h] = __float2half(g1);
    extra_out[(size_t)(row0 + 2) * H + h] = __float2half(g2);
    extra_out[(size_t)(row0 + 3) * H + h] = __float2half(g3);
}

// ---------------------------------------------------------------------------
// F: c_atom[i,h] = (h2@W0)[i,h] * sum_k p_atom[ag[i,k],h]*(bf[bg[i,k]]@M2)[h]
// Same pipelined-gather structure.
// ---------------------------------------------------------------------------
#define ISSUE_P(i, PA, BV) do {                                              \
    _Pragma("unroll")                                                        \
    for (int j = 0; j < MAX_NEI; ++j) {                                      \
        int idx = __shfl(my_ia, (i) * MAX_NEI + j, 64);                      \
        PA[j] = p_atom[(size_t)idx * H + h];                                 \
    }                                                                        \
    int ibk = __shfl(my_ib, (i) * MAX_NEI + kk, 64);                         \
    BV = (h < MAX_NEI * BFD) ? bf[(size_t)ibk * BFD + jj] : 0.f;             \
} while (0)

#define CONSUME_P(PA, BV, OUT) do {                                          \
    float a = 0.f;                                                           \
    _Pragma("unroll")                                                        \
    for (int j = 0; j < MAX_NEI; ++j) {                                      \
        float pb = 0.f;                                                      \
        _Pragma("unroll")                                                    \
        for (int q = 0; q < BFD; ++q)                                        \
            pb = fmaf(__shfl(BV, j * BFD + q, 64), m2c[q], pb);              \
        a = fmaf(__half2float(PA[j]), pb, a);                                \
    }                                                                        \
    OUT = a;                                                                 \
} while (0)

__global__ __launch_bounds__(1024, 8) void k_catom(
    const float* __restrict__ h2, const __half* __restrict__ p_atom,
    const float* __restrict__ bf, const float* __restrict__ M2,
    const int* __restrict__ ag, const int* __restrict__ bg,
    const float* __restrict__ W0, float* __restrict__ c_atom)
{
    __shared__ float sW[H * H];         // 16 KB
    __shared__ float4 sRow[WPB][H];     // 16 KB
    int tid = threadIdx.x;
    ((float4*)sW)[tid] = ((const float4*)W0)[tid];
    int w = tid >> 6, h = tid & 63;
    int kk = h / BFD;
    int jj = h - kk * BFD;
    int row0 = __builtin_amdgcn_readfirstlane((int)(blockIdx.x * RPB + w * RPW));

    int my_ia = 0, my_ib = 0;
    if (h < NG) {
        my_ia = ag[(size_t)row0 * MAX_NEI + h];
        my_ib = bg[(size_t)row0 * MAX_NEI + h];
    }
    float m2c[BFD];
#pragma unroll
    for (int j = 0; j < BFD; ++j) m2c[j] = M2[j * H + h];
    float x0 = NT_LD(&h2[(size_t)(row0 + 0) * H + h]);
    float x1 = NT_LD(&h2[(size_t)(row0 + 1) * H + h]);
    float x2 = NT_LD(&h2[(size_t)(row0 + 2) * H + h]);
    float x3 = NT_LD(&h2[(size_t)(row0 + 3) * H + h]);
    sRow[w][h] = make_float4(x0, x1, x2, x3);

    __half pa_A[MAX_NEI], pa_B[MAX_NEI];
    float bv_A, bv_B;
    ISSUE_P(0, pa_A, bv_A);
    ISSUE_P(1, pa_B, bv_B);

    __syncthreads();                    // sW ready; gathers in flight

    float f0 = 0.f, f1 = 0.f, f2 = 0.f, f3 = 0.f;
#pragma unroll 4
    for (int k = 0; k < H; ++k) {
        float u = sW[k * H + h];
        float4 s = sRow[w][k];
        f0 = fmaf(s.x, u, f0); f1 = fmaf(s.y, u, f1);
        f2 = fmaf(s.z, u, f2); f3 = fmaf(s.w, u, f3);
    }

    float s0, s1, s2, s3;
    CONSUME_P(pa_A, bv_A, s0);
    ISSUE_P(2, pa_A, bv_A);
    CONSUME_P(pa_B, bv_B, s1);
    ISSUE_P(3, pa_B, bv_B);
    CONSUME_P(pa_A, bv_A, s2);
    CONSUME_P(pa_B, bv_B, s3);

    c_atom[(size_t)(row0 + 0) * H + h] = f0 * s0;
    c_atom[(size_t)(row0 + 1) * H + h] = f1 * s1;
    c_atom[(size_t)(row0 + 2) * H + h] = f2 * s2;
    c_atom[(size_t)(row0 + 3) * H + h] = f3 * s3;
}

// ---------------------------------------------------------------------------
// H: c_mol[m] = sum over contiguous atom slice (mol_ids sorted, binary search)
// ---------------------------------------------------------------------------
__global__ void k_segsum(
    const float* __restrict__ c_atom, const int* __restrict__ mol_ids,
    float* __restrict__ c_mol)
{
    int m = blockIdx.x;
    int h = threadIdx.x;           // 64 threads
    int lo = 0, hi = N_ATOMS;
    while (lo < hi) { int mid = (lo + hi) >> 1; if (mol_ids[mid] < m) lo = mid + 1; else hi = mid; }
    int start = lo;
    hi = N_ATOMS;
    while (lo < hi) { int mid = (lo + hi) >> 1; if (mol_ids[mid] < m + 1) lo = mid + 1; else hi = mid; }
    int end = lo;
    float acc = 0.f;
    for (int a = start; a < end; ++a) acc += c_atom[a * H + h];
    c_mol[m * H + h] = acc;
}

extern "C" void kernel_launch(void* const* d_in, const int* in_sizes, int n_in,
                              void* d_out, int out_size, void* d_ws, size_t ws_size,
                              hipStream_t stream)
{
    const float* atom_feat = (const float*)d_in[0];
    const float* bond_feat = (const float*)d_in[1];
    const int*   ag        = (const int*)d_in[2];
    const int*   bg        = (const int*)d_in[3];
    const int*   mol_ids   = (const int*)d_in[4];
    const float* W_aemb    = (const float*)d_in[5];
    const float* W_bemb    = (const float*)d_in[6];
    const float* U1        = (const float*)d_in[7];
    const float* U2        = (const float*)d_in[8];
    const float* V         = (const float*)d_in[9];
    const float* W0        = (const float*)d_in[10];
    const float* W1        = (const float*)d_in[11];
    const float* W2        = (const float*)d_in[12];

    float* out    = (float*)d_out;
    float* c_mol  = out;
    float* c_atom = out + (size_t)N_MOLS * H;   // also g_atom pong scratch (fp16)

    float*  hA  = (float*)d_ws;                  // [N_ATOMS*H] fp32, in-place h
    __half* gA0 = (__half*)(hA + (size_t)N_ATOMS * H);   // [N_ATOMS*H] fp16 ping
    float*  M1  = (float*)(gA0 + (size_t)N_ATOMS * H);   // [6*64]
    float*  M2  = M1 + BFD * H;                          // [6*64]
    __half* gA1 = (__half*)c_atom;               // pong in d_out (dead by k_catom)

    const float* V1 = V;            // V rows 0..63   (h_bond_nei part)
    const float* V2 = V + H * H;    // V rows 64..127 (h_atom_nei part)

    k_tiny<<<1, 256, 0, stream>>>(W_bemb, V1, W1, M1, M2);

    k_atom_emb<<<N_ATOMS / RPB, 1024, 0, stream>>>(atom_feat, W_aemb, V2, hA, gA0);

    // iter 0: h1 = relu(h0@U1 + nei@U2); gA1 = h1@V2 (fp16)
    k_update<<<N_ATOMS / RPB, 1024, 0, stream>>>(hA, gA0, bond_feat, M1, ag, bg,
                                                 U1, U2, V2, hA, gA1);
    // iter 1: h2 = relu(h1@U1 + nei@U2); gA0 = p_atom = h2@W2 (fp16)
    k_update<<<N_ATOMS / RPB, 1024, 0, stream>>>(hA, gA1, bond_feat, M1, ag, bg,
                                                 U1, U2, W2, hA, gA0);

    // iter 2 (last): c_atom = (h2@W0) * sum_k p_atom[ag]*(bf[bg]@M2)
    k_catom<<<N_ATOMS / RPB, 1024, 0, stream>>>(hA, gA0, bond_feat, M2, ag, bg,
                                                W0, c_atom);

    k_segsum<<<N_MOLS, 64, 0, stream>>>(c_atom, mol_ids, c_mol);
}

// Round 10
// 726.240 us; speedup vs baseline: 4.5523x; 4.5523x over previous
//
#include <hip/hip_runtime.h>
#include <hip/hip_fp16.h>

#define N_ATOMS 200000
#define N_BONDS 400000
#define MAX_NEI 10
#define N_MOLS  8000
#define AFD 87
#define BFD 6
#define H 64
#define WPB 16          // waves per block (1024 threads)
#define RPW 4           // rows per wave
#define RPB (WPB*RPW)   // 64 rows per block
#define NG  (RPW*MAX_NEI)   // 40 neighbor slots per wave

#define NT_LD(p)     __builtin_nontemporal_load(p)
#define NT_ST(p, v)  __builtin_nontemporal_store((v), (p))

// ---------------------------------------------------------------------------
// T: M1 = W_bemb @ V1 ; M2 = W_bemb @ W1   (both [6][64], one block)
// ---------------------------------------------------------------------------
__global__ __launch_bounds__(256) void k_tiny(
    const float* __restrict__ Wb, const float* __restrict__ V1,
    const float* __restrict__ W1, float* __restrict__ M1, float* __restrict__ M2)
{
    int t = threadIdx.x;
    for (int idx = t; idx < BFD * H; idx += 256) {
        int k = idx >> 6, h = idx & 63;
        float a1 = 0.f, a2 = 0.f;
        for (int j = 0; j < H; ++j) {
            float w = Wb[k * H + j];
            a1 = fmaf(w, V1[j * H + h], a1);
            a2 = fmaf(w, W1[j * H + h], a2);
        }
        M1[idx] = a1;
        M2[idx] = a2;
    }
}

// ---------------------------------------------------------------------------
// A: h_atom = af@Wemb ; g_atom0 = h_atom@V2 (fp16 out). 4 rows/wave.
// ---------------------------------------------------------------------------
__global__ __launch_bounds__(1024, 8) void k_atom_emb(
    const float* __restrict__ af, const float* __restrict__ Wemb,
    const float* __restrict__ V2, float* __restrict__ h_atom,
    __half* __restrict__ g_atom)
{
    __shared__ float sW[AFD * H];          // 22272 B
    __shared__ float sV[H * H];            // 16384 B
    __shared__ float sT[WPB * AFD * 4];    // 22272 B
    int tid = threadIdx.x;
    for (int t = tid; t < AFD * H / 4; t += 1024)
        ((float4*)sW)[t] = ((const float4*)Wemb)[t];
    ((float4*)sV)[tid] = ((const float4*)V2)[tid];
    int w = tid >> 6, h = tid & 63;
    int row0 = __builtin_amdgcn_readfirstlane((int)(blockIdx.x * RPB + w * RPW));
    float* myT = sT + w * (AFD * 4);
    for (int c = h; c < AFD; c += 64) {
#pragma unroll
        for (int i = 0; i < RPW; ++i)
            myT[c * 4 + i] = NT_LD(&af[(size_t)(row0 + i) * AFD + c]);
    }
    __syncthreads();
    const float4* myTv = (const float4*)myT;
    float a0 = 0.f, a1 = 0.f, a2 = 0.f, a3 = 0.f;
#pragma unroll 4
    for (int k = 0; k < AFD; ++k) {
        float u = sW[k * H + h];
        float4 s = myTv[k];
        a0 = fmaf(s.x, u, a0); a1 = fmaf(s.y, u, a1);
        a2 = fmaf(s.z, u, a2); a3 = fmaf(s.w, u, a3);
    }
    NT_ST(&h_atom[(size_t)(row0 + 0) * H + h], a0);
    NT_ST(&h_atom[(size_t)(row0 + 1) * H + h], a1);
    NT_ST(&h_atom[(size_t)(row0 + 2) * H + h], a2);
    NT_ST(&h_atom[(size_t)(row0 + 3) * H + h], a3);
    ((float4*)myT)[h] = make_float4(a0, a1, a2, a3);
    float g0 = 0.f, g1 = 0.f, g2 = 0.f, g3 = 0.f;
#pragma unroll 4
    for (int k = 0; k < H; ++k) {
        float v = sV[k * H + h];
        float4 s = myTv[k];
        g0 = fmaf(s.x, v, g0); g1 = fmaf(s.y, v, g1);
        g2 = fmaf(s.z, v, g2); g3 = fmaf(s.w, v, g3);
    }
    g_atom[(size_t)(row0 + 0) * H + h] = __float2half(g0);
    g_atom[(size_t)(row0 + 1) * H + h] = __float2half(g1);
    g_atom[(size_t)(row0 + 2) * H + h] = __float2half(g2);
    g_atom[(size_t)(row0 + 3) * H + h] = __float2half(g3);
}

// ---------------------------------------------------------------------------
// E: h_new = relu(h@U1 + nei@U2); extra = h_new@Mx (fp16 out). 4 rows/wave.
// Indices: one coalesced 40-lane load per table, broadcast via readlane
// (constant lane) -> SGPR-based gather addressing, no dependent index loads,
// NO per-thread arrays (round-9 spill lesson). Consume is immediate.
// ---------------------------------------------------------------------------
#define GATHER_NEI(i, OUT) do {                                              \
    float a = 0.f;                                                           \
    _Pragma("unroll")                                                        \
    for (int k = 0; k < MAX_NEI; ++k) {                                      \
        int ia = __builtin_amdgcn_readlane(my_ia, (i) * MAX_NEI + k);        \
        int ib = __builtin_amdgcn_readlane(my_ib, (i) * MAX_NEI + k);        \
        float ga = __half2float(g_atom[(size_t)ia * H + h]);                 \
        const float* bp = bf + (size_t)ib * BFD;                             \
        float gb = 0.f;                                                      \
        _Pragma("unroll")                                                    \
        for (int j = 0; j < BFD; ++j) gb = fmaf(bp[j], m1c[j], gb);          \
        a += fmaxf(gb + ga, 0.f);                                            \
    }                                                                        \
    OUT = a;                                                                 \
} while (0)

__global__ __launch_bounds__(1024, 8) void k_update(
    const float* __restrict__ h_in, const __half* __restrict__ g_atom,
    const float* __restrict__ bf, const float* __restrict__ M1,
    const int* __restrict__ ag, const int* __restrict__ bg,
    const float* __restrict__ U1, const float* __restrict__ U2,
    const float* __restrict__ Mx,
    float* __restrict__ h_out, __half* __restrict__ extra_out)
{
    __shared__ float sU1[H * H];        // 16 KB
    __shared__ float sU2[H * H];        // 16 KB
    __shared__ float4 sRow[WPB][H];     // 16 KB
    __shared__ float4 sNei[WPB][H];     // 16 KB
    int tid = threadIdx.x;
    ((float4*)sU1)[tid] = ((const float4*)U1)[tid];
    ((float4*)sU2)[tid] = ((const float4*)U2)[tid];
    int w = tid >> 6, h = tid & 63;
    int row0 = __builtin_amdgcn_readfirstlane((int)(blockIdx.x * RPB + w * RPW));

    // all 40 indices per table in ONE coalesced 40-lane load
    int my_ia = 0, my_ib = 0;
    if (h < NG) {
        my_ia = ag[(size_t)row0 * MAX_NEI + h];
        my_ib = bg[(size_t)row0 * MAX_NEI + h];
    }
    float m1c[BFD];
#pragma unroll
    for (int j = 0; j < BFD; ++j) m1c[j] = M1[j * H + h];
    float x0 = NT_LD(&h_in[(size_t)(row0 + 0) * H + h]);
    float x1 = NT_LD(&h_in[(size_t)(row0 + 1) * H + h]);
    float x2 = NT_LD(&h_in[(size_t)(row0 + 2) * H + h]);
    float x3 = NT_LD(&h_in[(size_t)(row0 + 3) * H + h]);
    sRow[w][h] = make_float4(x0, x1, x2, x3);
    float n0, n1, n2, n3;
    GATHER_NEI(0, n0);
    GATHER_NEI(1, n1);
    GATHER_NEI(2, n2);
    GATHER_NEI(3, n3);
    sNei[w][h] = make_float4(n0, n1, n2, n3);
    __syncthreads();
    float o0 = 0.f, o1 = 0.f, o2 = 0.f, o3 = 0.f;
#pragma unroll 4
    for (int k = 0; k < H; ++k) {
        float u = sU1[k * H + h];
        float4 s = sRow[w][k];
        o0 = fmaf(s.x, u, o0); o1 = fmaf(s.y, u, o1);
        o2 = fmaf(s.z, u, o2); o3 = fmaf(s.w, u, o3);
    }
#pragma unroll 4
    for (int k = 0; k < H; ++k) {
        float u = sU2[k * H + h];
        float4 s = sNei[w][k];
        o0 = fmaf(s.x, u, o0); o1 = fmaf(s.y, u, o1);
        o2 = fmaf(s.z, u, o2); o3 = fmaf(s.w, u, o3);
    }
    o0 = fmaxf(o0, 0.f); o1 = fmaxf(o1, 0.f);
    o2 = fmaxf(o2, 0.f); o3 = fmaxf(o3, 0.f);
    NT_ST(&h_out[(size_t)(row0 + 0) * H + h], o0);
    NT_ST(&h_out[(size_t)(row0 + 1) * H + h], o1);
    NT_ST(&h_out[(size_t)(row0 + 2) * H + h], o2);
    NT_ST(&h_out[(size_t)(row0 + 3) * H + h], o3);
    sRow[w][h] = make_float4(o0, o1, o2, o3);          // reuse as snew (own wave)
    float g0 = 0.f, g1 = 0.f, g2 = 0.f, g3 = 0.f;
#pragma unroll 4
    for (int k = 0; k < H; ++k) {
        float u = Mx[k * H + h];                       // L1/L2-resident 16 KB
        float4 s = sRow[w][k];
        g0 = fmaf(s.x, u, g0); g1 = fmaf(s.y, u, g1);
        g2 = fmaf(s.z, u, g2); g3 = fmaf(s.w, u, g3);
    }
    extra_out[(size_t)(row0 + 0) * H + h] = __float2half(g0);
    extra_out[(size_t)(row0 + 1) * H + h] = __float2half(g1);
    extra_out[(size_t)(row0 + 2) * H + h] = __float2half(g2);
    extra_out[(size_t)(row0 + 3) * H + h] = __float2half(g3);
}

// ---------------------------------------------------------------------------
// F: c_atom[i,h] = (h2@W0)[i,h] * sum_k p_atom[ag[i,k],h]*(bf[bg[i,k]]@M2)[h]
// Same coalesced-index / readlane gather structure.
// ---------------------------------------------------------------------------
#define GATHER_PROD(i, OUT) do {                                             \
    float a = 0.f;                                                           \
    _Pragma("unroll")                                                        \
    for (int k = 0; k < MAX_NEI; ++k) {                                      \
        int ia = __builtin_amdgcn_readlane(my_ia, (i) * MAX_NEI + k);        \
        int ib = __builtin_amdgcn_readlane(my_ib, (i) * MAX_NEI + k);        \
        float pa = __half2float(p_atom[(size_t)ia * H + h]);                 \
        const float* bp = bf + (size_t)ib * BFD;                             \
        float pb = 0.f;                                                      \
        _Pragma("unroll")                                                    \
        for (int j = 0; j < BFD; ++j) pb = fmaf(bp[j], m2c[j], pb);          \
        a = fmaf(pa, pb, a);                                                 \
    }                                                                        \
    OUT = a;                                                                 \
} while (0)

__global__ __launch_bounds__(1024, 8) void k_catom(
    const float* __restrict__ h2, const __half* __restrict__ p_atom,
    const float* __restrict__ bf, const float* __restrict__ M2,
    const int* __restrict__ ag, const int* __restrict__ bg,
    const float* __restrict__ W0, float* __restrict__ c_atom)
{
    __shared__ float sW[H * H];         // 16 KB
    __shared__ float4 sRow[WPB][H];     // 16 KB
    int tid = threadIdx.x;
    ((float4*)sW)[tid] = ((const float4*)W0)[tid];
    int w = tid >> 6, h = tid & 63;
    int row0 = __builtin_amdgcn_readfirstlane((int)(blockIdx.x * RPB + w * RPW));

    int my_ia = 0, my_ib = 0;
    if (h < NG) {
        my_ia = ag[(size_t)row0 * MAX_NEI + h];
        my_ib = bg[(size_t)row0 * MAX_NEI + h];
    }
    float m2c[BFD];
#pragma unroll
    for (int j = 0; j < BFD; ++j) m2c[j] = M2[j * H + h];
    float x0 = NT_LD(&h2[(size_t)(row0 + 0) * H + h]);
    float x1 = NT_LD(&h2[(size_t)(row0 + 1) * H + h]);
    float x2 = NT_LD(&h2[(size_t)(row0 + 2) * H + h]);
    float x3 = NT_LD(&h2[(size_t)(row0 + 3) * H + h]);
    sRow[w][h] = make_float4(x0, x1, x2, x3);
    float s0, s1, s2, s3;
    GATHER_PROD(0, s0);
    GATHER_PROD(1, s1);
    GATHER_PROD(2, s2);
    GATHER_PROD(3, s3);
    __syncthreads();
    float f0 = 0.f, f1 = 0.f, f2 = 0.f, f3 = 0.f;
#pragma unroll 4
    for (int k = 0; k < H; ++k) {
        float u = sW[k * H + h];
        float4 s = sRow[w][k];
        f0 = fmaf(s.x, u, f0); f1 = fmaf(s.y, u, f1);
        f2 = fmaf(s.z, u, f2); f3 = fmaf(s.w, u, f3);
    }
    c_atom[(size_t)(row0 + 0) * H + h] = f0 * s0;
    c_atom[(size_t)(row0 + 1) * H + h] = f1 * s1;
    c_atom[(size_t)(row0 + 2) * H + h] = f2 * s2;
    c_atom[(size_t)(row0 + 3) * H + h] = f3 * s3;
}

// ---------------------------------------------------------------------------
// H: c_mol[m] = sum over contiguous atom slice (mol_ids sorted, binary search)
// ---------------------------------------------------------------------------
__global__ void k_segsum(
    const float* __restrict__ c_atom, const int* __restrict__ mol_ids,
    float* __restrict__ c_mol)
{
    int m = blockIdx.x;
    int h = threadIdx.x;           // 64 threads
    int lo = 0, hi = N_ATOMS;
    while (lo < hi) { int mid = (lo + hi) >> 1; if (mol_ids[mid] < m) lo = mid + 1; else hi = mid; }
    int start = lo;
    hi = N_ATOMS;
    while (lo < hi) { int mid = (lo + hi) >> 1; if (mol_ids[mid] < m + 1) lo = mid + 1; else hi = mid; }
    int end = lo;
    float acc = 0.f;
    for (int a = start; a < end; ++a) acc += c_atom[a * H + h];
    c_mol[m * H + h] = acc;
}

extern "C" void kernel_launch(void* const* d_in, const int* in_sizes, int n_in,
                              void* d_out, int out_size, void* d_ws, size_t ws_size,
                              hipStream_t stream)
{
    const float* atom_feat = (const float*)d_in[0];
    const float* bond_feat = (const float*)d_in[1];
    const int*   ag        = (const int*)d_in[2];
    const int*   bg        = (const int*)d_in[3];
    const int*   mol_ids   = (const int*)d_in[4];
    const float* W_aemb    = (const float*)d_in[5];
    const float* W_bemb    = (const float*)d_in[6];
    const float* U1        = (const float*)d_in[7];
    const float* U2        = (const float*)d_in[8];
    const float* V         = (const float*)d_in[9];
    const float* W0        = (const float*)d_in[10];
    const float* W1        = (const float*)d_in[11];
    const float* W2        = (const float*)d_in[12];

    float* out    = (float*)d_out;
    float* c_mol  = out;
    float* c_atom = out + (size_t)N_MOLS * H;   // also g_atom pong scratch (fp16)

    float*  hA  = (float*)d_ws;                  // [N_ATOMS*H] fp32, in-place h
    __half* gA0 = (__half*)(hA + (size_t)N_ATOMS * H);   // [N_ATOMS*H] fp16 ping
    float*  M1  = (float*)(gA0 + (size_t)N_ATOMS * H);   // [6*64]
    float*  M2  = M1 + BFD * H;                          // [6*64]
    __half* gA1 = (__half*)c_atom;               // pong in d_out (dead by k_catom)

    const float* V1 = V;            // V rows 0..63   (h_bond_nei part)
    const float* V2 = V + H * H;    // V rows 64..127 (h_atom_nei part)

    k_tiny<<<1, 256, 0, stream>>>(W_bemb, V1, W1, M1, M2);

    k_atom_emb<<<N_ATOMS / RPB, 1024, 0, stream>>>(atom_feat, W_aemb, V2, hA, gA0);

    // iter 0: h1 = relu(h0@U1 + nei@U2); gA1 = h1@V2 (fp16)
    k_update<<<N_ATOMS / RPB, 1024, 0, stream>>>(hA, gA0, bond_feat, M1, ag, bg,
                                                 U1, U2, V2, hA, gA1);
    // iter 1: h2 = relu(h1@U1 + nei@U2); gA0 = p_atom = h2@W2 (fp16)
    k_update<<<N_ATOMS / RPB, 1024, 0, stream>>>(hA, gA1, bond_feat, M1, ag, bg,
                                                 U1, U2, W2, hA, gA0);

    // iter 2 (last): c_atom = (h2@W0) * sum_k p_atom[ag]*(bf[bg]@M2)
    k_catom<<<N_ATOMS / RPB, 1024, 0, stream>>>(hA, gA0, bond_feat, M2, ag, bg,
                                                W0, c_atom);

    k_segsum<<<N_MOLS, 64, 0, stream>>>(c_atom, mol_ids, c_mol);
}

// Round 11
// 710.588 us; speedup vs baseline: 4.6526x; 1.0220x over previous
//
#include <hip/hip_runtime.h>
#include <hip/hip_fp16.h>

#define N_ATOMS 200000
#define N_BONDS 400000
#define MAX_NEI 10
#define N_MOLS  8000
#define AFD 87
#define BFD 6
#define H 64
#define WPB 16          // waves per block (1024 threads)
#define RPW 4           // rows per wave
#define RPB (WPB*RPW)   // 64 rows per block
#define NG  (RPW*MAX_NEI)   // 40 neighbor slots per wave

#define NT_LD(p)     __builtin_nontemporal_load(p)
#define NT_ST(p, v)  __builtin_nontemporal_store((v), (p))

// ---------------------------------------------------------------------------
// T: M1 = W_bemb @ V1 ; M2 = W_bemb @ W1   (both [6][64], one block)
// ---------------------------------------------------------------------------
__global__ __launch_bounds__(256) void k_tiny(
    const float* __restrict__ Wb, const float* __restrict__ V1,
    const float* __restrict__ W1, float* __restrict__ M1, float* __restrict__ M2)
{
    int t = threadIdx.x;
    for (int idx = t; idx < BFD * H; idx += 256) {
        int k = idx >> 6, h = idx & 63;
        float a1 = 0.f, a2 = 0.f;
        for (int j = 0; j < H; ++j) {
            float w = Wb[k * H + j];
            a1 = fmaf(w, V1[j * H + h], a1);
            a2 = fmaf(w, W1[j * H + h], a2);
        }
        M1[idx] = a1;
        M2[idx] = a2;
    }
}

// ---------------------------------------------------------------------------
// A: h_atom = af@Wemb ; g_atom0 = h_atom@V2 (fp16 out). 4 rows/wave.
// ---------------------------------------------------------------------------
__global__ __launch_bounds__(1024, 8) void k_atom_emb(
    const float* __restrict__ af, const float* __restrict__ Wemb,
    const float* __restrict__ V2, float* __restrict__ h_atom,
    __half* __restrict__ g_atom)
{
    __shared__ float sW[AFD * H];          // 22272 B
    __shared__ float sV[H * H];            // 16384 B
    __shared__ float sT[WPB * AFD * 4];    // 22272 B
    int tid = threadIdx.x;
    for (int t = tid; t < AFD * H / 4; t += 1024)
        ((float4*)sW)[t] = ((const float4*)Wemb)[t];
    ((float4*)sV)[tid] = ((const float4*)V2)[tid];
    int w = tid >> 6, h = tid & 63;
    int row0 = __builtin_amdgcn_readfirstlane((int)(blockIdx.x * RPB + w * RPW));
    float* myT = sT + w * (AFD * 4);
    for (int c = h; c < AFD; c += 64) {
#pragma unroll
        for (int i = 0; i < RPW; ++i)
            myT[c * 4 + i] = NT_LD(&af[(size_t)(row0 + i) * AFD + c]);
    }
    __syncthreads();
    const float4* myTv = (const float4*)myT;
    float a0 = 0.f, a1 = 0.f, a2 = 0.f, a3 = 0.f;
#pragma unroll 4
    for (int k = 0; k < AFD; ++k) {
        float u = sW[k * H + h];
        float4 s = myTv[k];
        a0 = fmaf(s.x, u, a0); a1 = fmaf(s.y, u, a1);
        a2 = fmaf(s.z, u, a2); a3 = fmaf(s.w, u, a3);
    }
    NT_ST(&h_atom[(size_t)(row0 + 0) * H + h], a0);
    NT_ST(&h_atom[(size_t)(row0 + 1) * H + h], a1);
    NT_ST(&h_atom[(size_t)(row0 + 2) * H + h], a2);
    NT_ST(&h_atom[(size_t)(row0 + 3) * H + h], a3);
    ((float4*)myT)[h] = make_float4(a0, a1, a2, a3);
    float g0 = 0.f, g1 = 0.f, g2 = 0.f, g3 = 0.f;
#pragma unroll 4
    for (int k = 0; k < H; ++k) {
        float v = sV[k * H + h];
        float4 s = myTv[k];
        g0 = fmaf(s.x, v, g0); g1 = fmaf(s.y, v, g1);
        g2 = fmaf(s.z, v, g2); g3 = fmaf(s.w, v, g3);
    }
    g_atom[(size_t)(row0 + 0) * H + h] = __float2half(g0);
    g_atom[(size_t)(row0 + 1) * H + h] = __float2half(g1);
    g_atom[(size_t)(row0 + 2) * H + h] = __float2half(g2);
    g_atom[(size_t)(row0 + 3) * H + h] = __float2half(g3);
}

// ---------------------------------------------------------------------------
// Pair-gather: ONE dword request serves TWO neighbor rows (lanes 0-31 cover
// row A's 64 fp16, lanes 32-63 row B's). Redistribute via 2 __shfl + half
// extraction. Halves VMEM request count 40 -> 20 per wave.
// ---------------------------------------------------------------------------
#define GATHER_NEI(i, OUT) do {                                              \
    float a = 0.f;                                                           \
    _Pragma("unroll")                                                        \
    for (int p = 0; p < MAX_NEI / 2; ++p) {                                  \
        int ia1 = __builtin_amdgcn_readlane(my_ia, (i) * MAX_NEI + 2 * p);   \
        int ia2 = __builtin_amdgcn_readlane(my_ia, (i) * MAX_NEI + 2 * p + 1);\
        int ib1 = __builtin_amdgcn_readlane(my_ib, (i) * MAX_NEI + 2 * p);   \
        int ib2 = __builtin_amdgcn_readlane(my_ib, (i) * MAX_NEI + 2 * p + 1);\
        unsigned off = (unsigned)(h < 32 ? ia1 : ia2) * (unsigned)(H * 2)    \
                       + (unsigned)(h & 31) * 4u;                            \
        unsigned dw = *(const unsigned*)((const char*)g_atom + off);         \
        const float* bp1 = bf + (size_t)ib1 * BFD;                           \
        const float* bp2 = bf + (size_t)ib2 * BFD;                           \
        float gb1 = 0.f, gb2 = 0.f;                                          \
        _Pragma("unroll")                                                    \
        for (int j = 0; j < BFD; ++j) {                                      \
            gb1 = fmaf(bp1[j], m1c[j], gb1);                                 \
            gb2 = fmaf(bp2[j], m1c[j], gb2);                                 \
        }                                                                    \
        unsigned d1 = (unsigned)__shfl((int)dw, (h >> 1), 64);               \
        unsigned d2 = (unsigned)__shfl((int)dw, 32 + (h >> 1), 64);          \
        unsigned short us1 = (unsigned short)(d1 >> ((h & 1) * 16));         \
        unsigned short us2 = (unsigned short)(d2 >> ((h & 1) * 16));         \
        float ga1 = __half2float(__builtin_bit_cast(__half, us1));           \
        float ga2 = __half2float(__builtin_bit_cast(__half, us2));           \
        a += fmaxf(gb1 + ga1, 0.f);                                          \
        a += fmaxf(gb2 + ga2, 0.f);                                          \
    }                                                                        \
    OUT = a;                                                                 \
} while (0)

__global__ __launch_bounds__(1024, 8) void k_update(
    const float* __restrict__ h_in, const __half* __restrict__ g_atom,
    const float* __restrict__ bf, const float* __restrict__ M1,
    const int* __restrict__ ag, const int* __restrict__ bg,
    const float* __restrict__ U1, const float* __restrict__ U2,
    const float* __restrict__ Mx,
    float* __restrict__ h_out, __half* __restrict__ extra_out)
{
    __shared__ float sU1[H * H];        // 16 KB
    __shared__ float sU2[H * H];        // 16 KB
    __shared__ float4 sRow[WPB][H];     // 16 KB
    __shared__ float4 sNei[WPB][H];     // 16 KB
    int tid = threadIdx.x;
    ((float4*)sU1)[tid] = ((const float4*)U1)[tid];
    ((float4*)sU2)[tid] = ((const float4*)U2)[tid];
    int w = tid >> 6, h = tid & 63;
    int row0 = __builtin_amdgcn_readfirstlane((int)(blockIdx.x * RPB + w * RPW));

    // all 40 indices per table in ONE coalesced 40-lane load
    int my_ia = 0, my_ib = 0;
    if (h < NG) {
        my_ia = ag[(size_t)row0 * MAX_NEI + h];
        my_ib = bg[(size_t)row0 * MAX_NEI + h];
    }
    float m1c[BFD];
#pragma unroll
    for (int j = 0; j < BFD; ++j) m1c[j] = M1[j * H + h];
    float x0 = NT_LD(&h_in[(size_t)(row0 + 0) * H + h]);
    float x1 = NT_LD(&h_in[(size_t)(row0 + 1) * H + h]);
    float x2 = NT_LD(&h_in[(size_t)(row0 + 2) * H + h]);
    float x3 = NT_LD(&h_in[(size_t)(row0 + 3) * H + h]);
    sRow[w][h] = make_float4(x0, x1, x2, x3);
    float n0, n1, n2, n3;
    GATHER_NEI(0, n0);
    GATHER_NEI(1, n1);
    GATHER_NEI(2, n2);
    GATHER_NEI(3, n3);
    sNei[w][h] = make_float4(n0, n1, n2, n3);
    __syncthreads();
    float o0 = 0.f, o1 = 0.f, o2 = 0.f, o3 = 0.f;
#pragma unroll 4
    for (int k = 0; k < H; ++k) {
        float u = sU1[k * H + h];
        float4 s = sRow[w][k];
        o0 = fmaf(s.x, u, o0); o1 = fmaf(s.y, u, o1);
        o2 = fmaf(s.z, u, o2); o3 = fmaf(s.w, u, o3);
    }
#pragma unroll 4
    for (int k = 0; k < H; ++k) {
        float u = sU2[k * H + h];
        float4 s = sNei[w][k];
        o0 = fmaf(s.x, u, o0); o1 = fmaf(s.y, u, o1);
        o2 = fmaf(s.z, u, o2); o3 = fmaf(s.w, u, o3);
    }
    o0 = fmaxf(o0, 0.f); o1 = fmaxf(o1, 0.f);
    o2 = fmaxf(o2, 0.f); o3 = fmaxf(o3, 0.f);
    NT_ST(&h_out[(size_t)(row0 + 0) * H + h], o0);
    NT_ST(&h_out[(size_t)(row0 + 1) * H + h], o1);
    NT_ST(&h_out[(size_t)(row0 + 2) * H + h], o2);
    NT_ST(&h_out[(size_t)(row0 + 3) * H + h], o3);
    sRow[w][h] = make_float4(o0, o1, o2, o3);          // reuse as snew (own wave)
    float g0 = 0.f, g1 = 0.f, g2 = 0.f, g3 = 0.f;
#pragma unroll 4
    for (int k = 0; k < H; ++k) {
        float u = Mx[k * H + h];                       // L1/L2-resident 16 KB
        float4 s = sRow[w][k];
        g0 = fmaf(s.x, u, g0); g1 = fmaf(s.y, u, g1);
        g2 = fmaf(s.z, u, g2); g3 = fmaf(s.w, u, g3);
    }
    extra_out[(size_t)(row0 + 0) * H + h] = __float2half(g0);
    extra_out[(size_t)(row0 + 1) * H + h] = __float2half(g1);
    extra_out[(size_t)(row0 + 2) * H + h] = __float2half(g2);
    extra_out[(size_t)(row0 + 3) * H + h] = __float2half(g3);
}

// ---------------------------------------------------------------------------
// F: c_atom[i,h] = (h2@W0)[i,h] * sum_k p_atom[ag[i,k],h]*(bf[bg[i,k]]@M2)[h]
// Same pair-gather structure.
// ---------------------------------------------------------------------------
#define GATHER_PROD(i, OUT) do {                                             \
    float a = 0.f;                                                           \
    _Pragma("unroll")                                                        \
    for (int p = 0; p < MAX_NEI / 2; ++p) {                                  \
        int ia1 = __builtin_amdgcn_readlane(my_ia, (i) * MAX_NEI + 2 * p);   \
        int ia2 = __builtin_amdgcn_readlane(my_ia, (i) * MAX_NEI + 2 * p + 1);\
        int ib1 = __builtin_amdgcn_readlane(my_ib, (i) * MAX_NEI + 2 * p);   \
        int ib2 = __builtin_amdgcn_readlane(my_ib, (i) * MAX_NEI + 2 * p + 1);\
        unsigned off = (unsigned)(h < 32 ? ia1 : ia2) * (unsigned)(H * 2)    \
                       + (unsigned)(h & 31) * 4u;                            \
        unsigned dw = *(const unsigned*)((const char*)p_atom + off);         \
        const float* bp1 = bf + (size_t)ib1 * BFD;                           \
        const float* bp2 = bf + (size_t)ib2 * BFD;                           \
        float pb1 = 0.f, pb2 = 0.f;                                          \
        _Pragma("unroll")                                                    \
        for (int j = 0; j < BFD; ++j) {                                      \
            pb1 = fmaf(bp1[j], m2c[j], pb1);                                 \
            pb2 = fmaf(bp2[j], m2c[j], pb2);                                 \
        }                                                                    \
        unsigned d1 = (unsigned)__shfl((int)dw, (h >> 1), 64);               \
        unsigned d2 = (unsigned)__shfl((int)dw, 32 + (h >> 1), 64);          \
        unsigned short us1 = (unsigned short)(d1 >> ((h & 1) * 16));         \
        unsigned short us2 = (unsigned short)(d2 >> ((h & 1) * 16));         \
        float pa1 = __half2float(__builtin_bit_cast(__half, us1));           \
        float pa2 = __half2float(__builtin_bit_cast(__half, us2));           \
        a = fmaf(pa1, pb1, a);                                               \
        a = fmaf(pa2, pb2, a);                                               \
    }                                                                        \
    OUT = a;                                                                 \
} while (0)

__global__ __launch_bounds__(1024, 8) void k_catom(
    const float* __restrict__ h2, const __half* __restrict__ p_atom,
    const float* __restrict__ bf, const float* __restrict__ M2,
    const int* __restrict__ ag, const int* __restrict__ bg,
    const float* __restrict__ W0, float* __restrict__ c_atom)
{
    __shared__ float sW[H * H];         // 16 KB
    __shared__ float4 sRow[WPB][H];     // 16 KB
    int tid = threadIdx.x;
    ((float4*)sW)[tid] = ((const float4*)W0)[tid];
    int w = tid >> 6, h = tid & 63;
    int row0 = __builtin_amdgcn_readfirstlane((int)(blockIdx.x * RPB + w * RPW));

    int my_ia = 0, my_ib = 0;
    if (h < NG) {
        my_ia = ag[(size_t)row0 * MAX_NEI + h];
        my_ib = bg[(size_t)row0 * MAX_NEI + h];
    }
    float m2c[BFD];
#pragma unroll
    for (int j = 0; j < BFD; ++j) m2c[j] = M2[j * H + h];
    float x0 = NT_LD(&h2[(size_t)(row0 + 0) * H + h]);
    float x1 = NT_LD(&h2[(size_t)(row0 + 1) * H + h]);
    float x2 = NT_LD(&h2[(size_t)(row0 + 2) * H + h]);
    float x3 = NT_LD(&h2[(size_t)(row0 + 3) * H + h]);
    sRow[w][h] = make_float4(x0, x1, x2, x3);
    float s0, s1, s2, s3;
    GATHER_PROD(0, s0);
    GATHER_PROD(1, s1);
    GATHER_PROD(2, s2);
    GATHER_PROD(3, s3);
    __syncthreads();
    float f0 = 0.f, f1 = 0.f, f2 = 0.f, f3 = 0.f;
#pragma unroll 4
    for (int k = 0; k < H; ++k) {
        float u = sW[k * H + h];
        float4 s = sRow[w][k];
        f0 = fmaf(s.x, u, f0); f1 = fmaf(s.y, u, f1);
        f2 = fmaf(s.z, u, f2); f3 = fmaf(s.w, u, f3);
    }
    c_atom[(size_t)(row0 + 0) * H + h] = f0 * s0;
    c_atom[(size_t)(row0 + 1) * H + h] = f1 * s1;
    c_atom[(size_t)(row0 + 2) * H + h] = f2 * s2;
    c_atom[(size_t)(row0 + 3) * H + h] = f3 * s3;
}

// ---------------------------------------------------------------------------
// H: c_mol[m] = sum over contiguous atom slice (mol_ids sorted, binary search)
// ---------------------------------------------------------------------------
__global__ void k_segsum(
    const float* __restrict__ c_atom, const int* __restrict__ mol_ids,
    float* __restrict__ c_mol)
{
    int m = blockIdx.x;
    int h = threadIdx.x;           // 64 threads
    int lo = 0, hi = N_ATOMS;
    while (lo < hi) { int mid = (lo + hi) >> 1; if (mol_ids[mid] < m) lo = mid + 1; else hi = mid; }
    int start = lo;
    hi = N_ATOMS;
    while (lo < hi) { int mid = (lo + hi) >> 1; if (mol_ids[mid] < m + 1) lo = mid + 1; else hi = mid; }
    int end = lo;
    float acc = 0.f;
    for (int a = start; a < end; ++a) acc += c_atom[a * H + h];
    c_mol[m * H + h] = acc;
}

extern "C" void kernel_launch(void* const* d_in, const int* in_sizes, int n_in,
                              void* d_out, int out_size, void* d_ws, size_t ws_size,
                              hipStream_t stream)
{
    const float* atom_feat = (const float*)d_in[0];
    const float* bond_feat = (const float*)d_in[1];
    const int*   ag        = (const int*)d_in[2];
    const int*   bg        = (const int*)d_in[3];
    const int*   mol_ids   = (const int*)d_in[4];
    const float* W_aemb    = (const float*)d_in[5];
    const float* W_bemb    = (const float*)d_in[6];
    const float* U1        = (const float*)d_in[7];
    const float* U2        = (const float*)d_in[8];
    const float* V         = (const float*)d_in[9];
    const float* W0        = (const float*)d_in[10];
    const float* W1        = (const float*)d_in[11];
    const float* W2        = (const float*)d_in[12];

    float* out    = (float*)d_out;
    float* c_mol  = out;
    float* c_atom = out + (size_t)N_MOLS * H;   // also g_atom pong scratch (fp16)

    float*  hA  = (float*)d_ws;                  // [N_ATOMS*H] fp32, in-place h
    __half* gA0 = (__half*)(hA + (size_t)N_ATOMS * H);   // [N_ATOMS*H] fp16 ping
    float*  M1  = (float*)(gA0 + (size_t)N_ATOMS * H);   // [6*64]
    float*  M2  = M1 + BFD * H;                          // [6*64]
    __half* gA1 = (__half*)c_atom;               // pong in d_out (dead by k_catom)

    const float* V1 = V;            // V rows 0..63   (h_bond_nei part)
    const float* V2 = V + H * H;    // V rows 64..127 (h_atom_nei part)

    k_tiny<<<1, 256, 0, stream>>>(W_bemb, V1, W1, M1, M2);

    k_atom_emb<<<N_ATOMS / RPB, 1024, 0, stream>>>(atom_feat, W_aemb, V2, hA, gA0);

    // iter 0: h1 = relu(h0@U1 + nei@U2); gA1 = h1@V2 (fp16)
    k_update<<<N_ATOMS / RPB, 1024, 0, stream>>>(hA, gA0, bond_feat, M1, ag, bg,
                                                 U1, U2, V2, hA, gA1);
    // iter 1: h2 = relu(h1@U1 + nei@U2); gA0 = p_atom = h2@W2 (fp16)
    k_update<<<N_ATOMS / RPB, 1024, 0, stream>>>(hA, gA1, bond_feat, M1, ag, bg,
                                                 U1, U2, W2, hA, gA0);

    // iter 2 (last): c_atom = (h2@W0) * sum_k p_atom[ag]*(bf[bg]@M2)
    k_catom<<<N_ATOMS / RPB, 1024, 0, stream>>>(hA, gA0, bond_feat, M2, ag, bg,
                                                W0, c_atom);

    k_segsum<<<N_MOLS, 64, 0, stream>>>(c_atom, mol_ids, c_mol);
}

// Round 12
// 691.347 us; speedup vs baseline: 4.7821x; 1.0278x over previous
//
#include <hip/hip_runtime.h>
#include <hip/hip_fp16.h>

#define N_ATOMS 200000
#define N_BONDS 400000
#define MAX_NEI 10
#define N_MOLS  8000
#define AFD 87
#define BFD 6
#define H 64
#define WPB 16          // waves per block (1024 threads)
#define RPW 4           // rows per wave
#define RPB (WPB*RPW)   // 64 rows per block
#define NG  (RPW*MAX_NEI)   // 40 neighbor slots per wave

#define NT_LD(p)     __builtin_nontemporal_load(p)
#define NT_ST(p, v)  __builtin_nontemporal_store((v), (p))

// ---------------------------------------------------------------------------
// T: M1 = W_bemb @ V1 ; M2 = W_bemb @ W1   (both [6][64], one block)
// ---------------------------------------------------------------------------
__global__ __launch_bounds__(256) void k_tiny(
    const float* __restrict__ Wb, const float* __restrict__ V1,
    const float* __restrict__ W1, float* __restrict__ M1, float* __restrict__ M2)
{
    int t = threadIdx.x;
    for (int idx = t; idx < BFD * H; idx += 256) {
        int k = idx >> 6, h = idx & 63;
        float a1 = 0.f, a2 = 0.f;
        for (int j = 0; j < H; ++j) {
            float w = Wb[k * H + j];
            a1 = fmaf(w, V1[j * H + h], a1);
            a2 = fmaf(w, W1[j * H + h], a2);
        }
        M1[idx] = a1;
        M2[idx] = a2;
    }
}

// ---------------------------------------------------------------------------
// A: h_atom(fp16) = af@Wemb ; g_atom0(fp16) = h_atom@V2.  4 rows/wave.
// ---------------------------------------------------------------------------
__global__ __launch_bounds__(1024, 8) void k_atom_emb(
    const float* __restrict__ af, const float* __restrict__ Wemb,
    const float* __restrict__ V2, unsigned short* __restrict__ h_atom,
    __half* __restrict__ g_atom)
{
    __shared__ float sW[AFD * H];          // 22272 B
    __shared__ float sV[H * H];            // 16384 B
    __shared__ float sT[WPB * AFD * 4];    // 22272 B
    int tid = threadIdx.x;
    for (int t = tid; t < AFD * H / 4; t += 1024)
        ((float4*)sW)[t] = ((const float4*)Wemb)[t];
    ((float4*)sV)[tid] = ((const float4*)V2)[tid];
    int w = tid >> 6, h = tid & 63;
    int row0 = __builtin_amdgcn_readfirstlane((int)(blockIdx.x * RPB + w * RPW));
    float* myT = sT + w * (AFD * 4);
    for (int c = h; c < AFD; c += 64) {
#pragma unroll
        for (int i = 0; i < RPW; ++i)
            myT[c * 4 + i] = NT_LD(&af[(size_t)(row0 + i) * AFD + c]);
    }
    __syncthreads();
    const float4* myTv = (const float4*)myT;
    float a0 = 0.f, a1 = 0.f, a2 = 0.f, a3 = 0.f;
#pragma unroll 4
    for (int k = 0; k < AFD; ++k) {
        float u = sW[k * H + h];
        float4 s = myTv[k];
        a0 = fmaf(s.x, u, a0); a1 = fmaf(s.y, u, a1);
        a2 = fmaf(s.z, u, a2); a3 = fmaf(s.w, u, a3);
    }
    NT_ST(&h_atom[(size_t)(row0 + 0) * H + h], __builtin_bit_cast(unsigned short, __float2half(a0)));
    NT_ST(&h_atom[(size_t)(row0 + 1) * H + h], __builtin_bit_cast(unsigned short, __float2half(a1)));
    NT_ST(&h_atom[(size_t)(row0 + 2) * H + h], __builtin_bit_cast(unsigned short, __float2half(a2)));
    NT_ST(&h_atom[(size_t)(row0 + 3) * H + h], __builtin_bit_cast(unsigned short, __float2half(a3)));
    ((float4*)myT)[h] = make_float4(a0, a1, a2, a3);
    float g0 = 0.f, g1 = 0.f, g2 = 0.f, g3 = 0.f;
#pragma unroll 4
    for (int k = 0; k < H; ++k) {
        float v = sV[k * H + h];
        float4 s = myTv[k];
        g0 = fmaf(s.x, v, g0); g1 = fmaf(s.y, v, g1);
        g2 = fmaf(s.z, v, g2); g3 = fmaf(s.w, v, g3);
    }
    g_atom[(size_t)(row0 + 0) * H + h] = __float2half(g0);
    g_atom[(size_t)(row0 + 1) * H + h] = __float2half(g1);
    g_atom[(size_t)(row0 + 2) * H + h] = __float2half(g2);
    g_atom[(size_t)(row0 + 3) * H + h] = __float2half(g3);
}

// ---------------------------------------------------------------------------
// Pipelined pair-gather building blocks (named scalars only — no arrays).
// PLOAD: one dword request serves two neighbor rows (lanes 0-31 row A,
// lanes 32-63 row B). BDOT: the two bond-feature dots for the same pair
// (independent of the gather). CONS_*: redistribute via 2 shfl + combine.
// ---------------------------------------------------------------------------
#define PLOAD(SRC, g_, p_, DW) do {                                          \
    int _iaA = __builtin_amdgcn_readlane(my_ia, (g_) * MAX_NEI + 2 * (p_));  \
    int _iaB = __builtin_amdgcn_readlane(my_ia, (g_) * MAX_NEI + 2 * (p_) + 1);\
    unsigned _off = (unsigned)(h < 32 ? _iaA : _iaB) * (unsigned)(H * 2)     \
                    + (unsigned)(h & 31) * 4u;                               \
    DW = *(const unsigned*)((const char*)(SRC) + _off);                      \
} while (0)

#define BDOT(MC, g_, p_, G1, G2) do {                                        \
    int _ibA = __builtin_amdgcn_readlane(my_ib, (g_) * MAX_NEI + 2 * (p_));  \
    int _ibB = __builtin_amdgcn_readlane(my_ib, (g_) * MAX_NEI + 2 * (p_) + 1);\
    const float* _b1 = bf + (size_t)_ibA * BFD;                              \
    const float* _b2 = bf + (size_t)_ibB * BFD;                              \
    G1 = 0.f; G2 = 0.f;                                                      \
    _Pragma("unroll")                                                        \
    for (int _j = 0; _j < BFD; ++_j) {                                       \
        G1 = fmaf(_b1[_j], MC[_j], G1);                                      \
        G2 = fmaf(_b2[_j], MC[_j], G2);                                      \
    }                                                                        \
} while (0)

#define CONS_NEI(DW, G1, G2, ACC) do {                                       \
    unsigned _d1 = (unsigned)__shfl((int)(DW), (h >> 1), 64);                \
    unsigned _d2 = (unsigned)__shfl((int)(DW), 32 + (h >> 1), 64);           \
    unsigned short _u1 = (unsigned short)(_d1 >> ((h & 1) * 16));            \
    unsigned short _u2 = (unsigned short)(_d2 >> ((h & 1) * 16));            \
    ACC += fmaxf(G1 + __half2float(__builtin_bit_cast(__half, _u1)), 0.f);   \
    ACC += fmaxf(G2 + __half2float(__builtin_bit_cast(__half, _u2)), 0.f);   \
} while (0)

#define CONS_PROD(DW, G1, G2, ACC) do {                                      \
    unsigned _d1 = (unsigned)__shfl((int)(DW), (h >> 1), 64);                \
    unsigned _d2 = (unsigned)__shfl((int)(DW), 32 + (h >> 1), 64);           \
    unsigned short _u1 = (unsigned short)(_d1 >> ((h & 1) * 16));            \
    unsigned short _u2 = (unsigned short)(_d2 >> ((h & 1) * 16));            \
    ACC = fmaf(__half2float(__builtin_bit_cast(__half, _u1)), G1, ACC);      \
    ACC = fmaf(__half2float(__builtin_bit_cast(__half, _u2)), G2, ACC);      \
} while (0)

// ---------------------------------------------------------------------------
// E: h_new = relu(h@U1 + nei@U2); extra = h_new@Mx (fp16). 4 rows/wave.
// 1-deep software-pipelined gathers: issue p+1 loads + bond dots before
// consuming p. All pipeline state in named scalars.
// ---------------------------------------------------------------------------
__global__ __launch_bounds__(1024, 8) void k_update(
    const unsigned short* __restrict__ h_in, const __half* __restrict__ g_atom,
    const float* __restrict__ bf, const float* __restrict__ M1,
    const int* __restrict__ ag, const int* __restrict__ bg,
    const float* __restrict__ U1, const float* __restrict__ U2,
    const float* __restrict__ Mx,
    unsigned short* __restrict__ h_out, __half* __restrict__ extra_out)
{
    __shared__ float sU1[H * H];        // 16 KB
    __shared__ float sU2[H * H];        // 16 KB
    __shared__ float4 sRow[WPB][H];     // 16 KB
    __shared__ float4 sNei[WPB][H];     // 16 KB
    int tid = threadIdx.x;
    ((float4*)sU1)[tid] = ((const float4*)U1)[tid];
    ((float4*)sU2)[tid] = ((const float4*)U2)[tid];
    int w = tid >> 6, h = tid & 63;
    int row0 = __builtin_amdgcn_readfirstlane((int)(blockIdx.x * RPB + w * RPW));

    int my_ia = 0, my_ib = 0;
    if (h < NG) {
        my_ia = ag[(size_t)row0 * MAX_NEI + h];
        my_ib = bg[(size_t)row0 * MAX_NEI + h];
    }
    float m1c[BFD];
#pragma unroll
    for (int j = 0; j < BFD; ++j) m1c[j] = M1[j * H + h];
    float x0 = __half2float(__builtin_bit_cast(__half, NT_LD(&h_in[(size_t)(row0 + 0) * H + h])));
    float x1 = __half2float(__builtin_bit_cast(__half, NT_LD(&h_in[(size_t)(row0 + 1) * H + h])));
    float x2 = __half2float(__builtin_bit_cast(__half, NT_LD(&h_in[(size_t)(row0 + 2) * H + h])));
    float x3 = __half2float(__builtin_bit_cast(__half, NT_LD(&h_in[(size_t)(row0 + 3) * H + h])));
    sRow[w][h] = make_float4(x0, x1, x2, x3);

    // --- pipelined gather (5 pair-steps, 4 row-groups) ---
    unsigned dwa0, dwa1, dwa2, dwa3;
    float ga0_1, ga0_2, ga1_1, ga1_2, ga2_1, ga2_2, ga3_1, ga3_2;
    PLOAD(g_atom, 0, 0, dwa0); PLOAD(g_atom, 1, 0, dwa1);
    PLOAD(g_atom, 2, 0, dwa2); PLOAD(g_atom, 3, 0, dwa3);
    BDOT(m1c, 0, 0, ga0_1, ga0_2); BDOT(m1c, 1, 0, ga1_1, ga1_2);
    BDOT(m1c, 2, 0, ga2_1, ga2_2); BDOT(m1c, 3, 0, ga3_1, ga3_2);
    float n0 = 0.f, n1 = 0.f, n2 = 0.f, n3 = 0.f;
#pragma unroll
    for (int p = 0; p < MAX_NEI / 2; ++p) {
        unsigned dwb0, dwb1, dwb2, dwb3;
        float gb0_1, gb0_2, gb1_1, gb1_2, gb2_1, gb2_2, gb3_1, gb3_2;
        if (p < MAX_NEI / 2 - 1) {
            PLOAD(g_atom, 0, p + 1, dwb0); PLOAD(g_atom, 1, p + 1, dwb1);
            PLOAD(g_atom, 2, p + 1, dwb2); PLOAD(g_atom, 3, p + 1, dwb3);
            BDOT(m1c, 0, p + 1, gb0_1, gb0_2); BDOT(m1c, 1, p + 1, gb1_1, gb1_2);
            BDOT(m1c, 2, p + 1, gb2_1, gb2_2); BDOT(m1c, 3, p + 1, gb3_1, gb3_2);
        } else {
            dwb0 = dwb1 = dwb2 = dwb3 = 0u;
            gb0_1 = gb0_2 = gb1_1 = gb1_2 = 0.f;
            gb2_1 = gb2_2 = gb3_1 = gb3_2 = 0.f;
        }
        CONS_NEI(dwa0, ga0_1, ga0_2, n0);
        CONS_NEI(dwa1, ga1_1, ga1_2, n1);
        CONS_NEI(dwa2, ga2_1, ga2_2, n2);
        CONS_NEI(dwa3, ga3_1, ga3_2, n3);
        dwa0 = dwb0; dwa1 = dwb1; dwa2 = dwb2; dwa3 = dwb3;
        ga0_1 = gb0_1; ga0_2 = gb0_2; ga1_1 = gb1_1; ga1_2 = gb1_2;
        ga2_1 = gb2_1; ga2_2 = gb2_2; ga3_1 = gb3_1; ga3_2 = gb3_2;
    }
    sNei[w][h] = make_float4(n0, n1, n2, n3);
    __syncthreads();
    float o0 = 0.f, o1 = 0.f, o2 = 0.f, o3 = 0.f;
#pragma unroll 4
    for (int k = 0; k < H; ++k) {
        float u = sU1[k * H + h];
        float4 s = sRow[w][k];
        o0 = fmaf(s.x, u, o0); o1 = fmaf(s.y, u, o1);
        o2 = fmaf(s.z, u, o2); o3 = fmaf(s.w, u, o3);
    }
#pragma unroll 4
    for (int k = 0; k < H; ++k) {
        float u = sU2[k * H + h];
        float4 s = sNei[w][k];
        o0 = fmaf(s.x, u, o0); o1 = fmaf(s.y, u, o1);
        o2 = fmaf(s.z, u, o2); o3 = fmaf(s.w, u, o3);
    }
    o0 = fmaxf(o0, 0.f); o1 = fmaxf(o1, 0.f);
    o2 = fmaxf(o2, 0.f); o3 = fmaxf(o3, 0.f);
    NT_ST(&h_out[(size_t)(row0 + 0) * H + h], __builtin_bit_cast(unsigned short, __float2half(o0)));
    NT_ST(&h_out[(size_t)(row0 + 1) * H + h], __builtin_bit_cast(unsigned short, __float2half(o1)));
    NT_ST(&h_out[(size_t)(row0 + 2) * H + h], __builtin_bit_cast(unsigned short, __float2half(o2)));
    NT_ST(&h_out[(size_t)(row0 + 3) * H + h], __builtin_bit_cast(unsigned short, __float2half(o3)));
    sRow[w][h] = make_float4(o0, o1, o2, o3);          // reuse as snew (own wave)
    float g0 = 0.f, g1 = 0.f, g2 = 0.f, g3 = 0.f;
#pragma unroll 4
    for (int k = 0; k < H; ++k) {
        float u = Mx[k * H + h];                       // L1/L2-resident 16 KB
        float4 s = sRow[w][k];
        g0 = fmaf(s.x, u, g0); g1 = fmaf(s.y, u, g1);
        g2 = fmaf(s.z, u, g2); g3 = fmaf(s.w, u, g3);
    }
    extra_out[(size_t)(row0 + 0) * H + h] = __float2half(g0);
    extra_out[(size_t)(row0 + 1) * H + h] = __float2half(g1);
    extra_out[(size_t)(row0 + 2) * H + h] = __float2half(g2);
    extra_out[(size_t)(row0 + 3) * H + h] = __float2half(g3);
}

// ---------------------------------------------------------------------------
// F: c_atom[i,h] = (h2@W0)[i,h] * sum_k p_atom[ag[i,k],h]*(bf[bg[i,k]]@M2)[h]
// Same pipelined pair-gather structure.
// ---------------------------------------------------------------------------
__global__ __launch_bounds__(1024, 8) void k_catom(
    const unsigned short* __restrict__ h2, const __half* __restrict__ p_atom,
    const float* __restrict__ bf, const float* __restrict__ M2,
    const int* __restrict__ ag, const int* __restrict__ bg,
    const float* __restrict__ W0, float* __restrict__ c_atom)
{
    __shared__ float sW[H * H];         // 16 KB
    __shared__ float4 sRow[WPB][H];     // 16 KB
    int tid = threadIdx.x;
    ((float4*)sW)[tid] = ((const float4*)W0)[tid];
    int w = tid >> 6, h = tid & 63;
    int row0 = __builtin_amdgcn_readfirstlane((int)(blockIdx.x * RPB + w * RPW));

    int my_ia = 0, my_ib = 0;
    if (h < NG) {
        my_ia = ag[(size_t)row0 * MAX_NEI + h];
        my_ib = bg[(size_t)row0 * MAX_NEI + h];
    }
    float m2c[BFD];
#pragma unroll
    for (int j = 0; j < BFD; ++j) m2c[j] = M2[j * H + h];
    float x0 = __half2float(__builtin_bit_cast(__half, NT_LD(&h2[(size_t)(row0 + 0) * H + h])));
    float x1 = __half2float(__builtin_bit_cast(__half, NT_LD(&h2[(size_t)(row0 + 1) * H + h])));
    float x2 = __half2float(__builtin_bit_cast(__half, NT_LD(&h2[(size_t)(row0 + 2) * H + h])));
    float x3 = __half2float(__builtin_bit_cast(__half, NT_LD(&h2[(size_t)(row0 + 3) * H + h])));
    sRow[w][h] = make_float4(x0, x1, x2, x3);

    unsigned dwa0, dwa1, dwa2, dwa3;
    float ga0_1, ga0_2, ga1_1, ga1_2, ga2_1, ga2_2, ga3_1, ga3_2;
    PLOAD(p_atom, 0, 0, dwa0); PLOAD(p_atom, 1, 0, dwa1);
    PLOAD(p_atom, 2, 0, dwa2); PLOAD(p_atom, 3, 0, dwa3);
    BDOT(m2c, 0, 0, ga0_1, ga0_2); BDOT(m2c, 1, 0, ga1_1, ga1_2);
    BDOT(m2c, 2, 0, ga2_1, ga2_2); BDOT(m2c, 3, 0, ga3_1, ga3_2);
    float s0 = 0.f, s1 = 0.f, s2 = 0.f, s3 = 0.f;
#pragma unroll
    for (int p = 0; p < MAX_NEI / 2; ++p) {
        unsigned dwb0, dwb1, dwb2, dwb3;
        float gb0_1, gb0_2, gb1_1, gb1_2, gb2_1, gb2_2, gb3_1, gb3_2;
        if (p < MAX_NEI / 2 - 1) {
            PLOAD(p_atom, 0, p + 1, dwb0); PLOAD(p_atom, 1, p + 1, dwb1);
            PLOAD(p_atom, 2, p + 1, dwb2); PLOAD(p_atom, 3, p + 1, dwb3);
            BDOT(m2c, 0, p + 1, gb0_1, gb0_2); BDOT(m2c, 1, p + 1, gb1_1, gb1_2);
            BDOT(m2c, 2, p + 1, gb2_1, gb2_2); BDOT(m2c, 3, p + 1, gb3_1, gb3_2);
        } else {
            dwb0 = dwb1 = dwb2 = dwb3 = 0u;
            gb0_1 = gb0_2 = gb1_1 = gb1_2 = 0.f;
            gb2_1 = gb2_2 = gb3_1 = gb3_2 = 0.f;
        }
        CONS_PROD(dwa0, ga0_1, ga0_2, s0);
        CONS_PROD(dwa1, ga1_1, ga1_2, s1);
        CONS_PROD(dwa2, ga2_1, ga2_2, s2);
        CONS_PROD(dwa3, ga3_1, ga3_2, s3);
        dwa0 = dwb0; dwa1 = dwb1; dwa2 = dwb2; dwa3 = dwb3;
        ga0_1 = gb0_1; ga0_2 = gb0_2; ga1_1 = gb1_1; ga1_2 = gb1_2;
        ga2_1 = gb2_1; ga2_2 = gb2_2; ga3_1 = gb3_1; ga3_2 = gb3_2;
    }
    __syncthreads();
    float f0 = 0.f, f1 = 0.f, f2 = 0.f, f3 = 0.f;
#pragma unroll 4
    for (int k = 0; k < H; ++k) {
        float u = sW[k * H + h];
        float4 s = sRow[w][k];
        f0 = fmaf(s.x, u, f0); f1 = fmaf(s.y, u, f1);
        f2 = fmaf(s.z, u, f2); f3 = fmaf(s.w, u, f3);
    }
    c_atom[(size_t)(row0 + 0) * H + h] = f0 * s0;
    c_atom[(size_t)(row0 + 1) * H + h] = f1 * s1;
    c_atom[(size_t)(row0 + 2) * H + h] = f2 * s2;
    c_atom[(size_t)(row0 + 3) * H + h] = f3 * s3;
}

// ---------------------------------------------------------------------------
// H: c_mol[m] = sum over contiguous atom slice (mol_ids sorted, binary search)
// ---------------------------------------------------------------------------
__global__ void k_segsum(
    const float* __restrict__ c_atom, const int* __restrict__ mol_ids,
    float* __restrict__ c_mol)
{
    int m = blockIdx.x;
    int h = threadIdx.x;           // 64 threads
    int lo = 0, hi = N_ATOMS;
    while (lo < hi) { int mid = (lo + hi) >> 1; if (mol_ids[mid] < m) lo = mid + 1; else hi = mid; }
    int start = lo;
    hi = N_ATOMS;
    while (lo < hi) { int mid = (lo + hi) >> 1; if (mol_ids[mid] < m + 1) lo = mid + 1; else hi = mid; }
    int end = lo;
    float acc = 0.f;
    for (int a = start; a < end; ++a) acc += c_atom[a * H + h];
    c_mol[m * H + h] = acc;
}

extern "C" void kernel_launch(void* const* d_in, const int* in_sizes, int n_in,
                              void* d_out, int out_size, void* d_ws, size_t ws_size,
                              hipStream_t stream)
{
    const float* atom_feat = (const float*)d_in[0];
    const float* bond_feat = (const float*)d_in[1];
    const int*   ag        = (const int*)d_in[2];
    const int*   bg        = (const int*)d_in[3];
    const int*   mol_ids   = (const int*)d_in[4];
    const float* W_aemb    = (const float*)d_in[5];
    const float* W_bemb    = (const float*)d_in[6];
    const float* U1        = (const float*)d_in[7];
    const float* U2        = (const float*)d_in[8];
    const float* V         = (const float*)d_in[9];
    const float* W0        = (const float*)d_in[10];
    const float* W1        = (const float*)d_in[11];
    const float* W2        = (const float*)d_in[12];

    float* out    = (float*)d_out;
    float* c_mol  = out;
    float* c_atom = out + (size_t)N_MOLS * H;   // also g_atom pong scratch (fp16)

    unsigned short* hA = (unsigned short*)d_ws;          // [N_ATOMS*H] fp16 h
    __half* gA0 = (__half*)(hA + (size_t)N_ATOMS * H);   // [N_ATOMS*H] fp16 ping
    float*  M1  = (float*)(gA0 + (size_t)N_ATOMS * H);   // [6*64]
    float*  M2  = M1 + BFD * H;                          // [6*64]
    __half* gA1 = (__half*)c_atom;               // pong in d_out (dead by k_catom)

    const float* V1 = V;            // V rows 0..63   (h_bond_nei part)
    const float* V2 = V + H * H;    // V rows 64..127 (h_atom_nei part)

    k_tiny<<<1, 256, 0, stream>>>(W_bemb, V1, W1, M1, M2);

    k_atom_emb<<<N_ATOMS / RPB, 1024, 0, stream>>>(atom_feat, W_aemb, V2, hA, gA0);

    // iter 0: h1 = relu(h0@U1 + nei@U2); gA1 = h1@V2 (fp16)
    k_update<<<N_ATOMS / RPB, 1024, 0, stream>>>(hA, gA0, bond_feat, M1, ag, bg,
                                                 U1, U2, V2, hA, gA1);
    // iter 1: h2 = relu(h1@U1 + nei@U2); gA0 = p_atom = h2@W2 (fp16)
    k_update<<<N_ATOMS / RPB, 1024, 0, stream>>>(hA, gA1, bond_feat, M1, ag, bg,
                                                 U1, U2, W2, hA, gA0);

    // iter 2 (last): c_atom = (h2@W0) * sum_k p_atom[ag]*(bf[bg]@M2)
    k_catom<<<N_ATOMS / RPB, 1024, 0, stream>>>(hA, gA0, bond_feat, M2, ag, bg,
                                                W0, c_atom);

    k_segsum<<<N_MOLS, 64, 0, stream>>>(c_atom, mol_ids, c_mol);
}